// Round 6
// baseline (294.765 us; speedup 1.0000x reference)
//
#include <hip/hip_runtime.h>
#include <math.h>

typedef __attribute__((ext_vector_type(8)))  _Float16       half8;
typedef __attribute__((ext_vector_type(8)))  unsigned short ushort8;
typedef __attribute__((ext_vector_type(4)))  float          f32x4;
typedef __attribute__((ext_vector_type(16))) float          f32x16;

constexpr int D_DIM = 2048;
constexpr int NEXP  = 64;
constexpr int TOPK  = 8;
constexpr int NTOK  = 16384;        // B*S
constexpr int TM    = 32;           // tokens per WG
constexpr int NCH   = 32;           // chunks of 64 K (4 ksteps of 16)
constexpr int OSTR  = 132;          // logit tile row stride (floats)
constexpr float WSCALE  = 4096.0f;
constexpr float INV_WSC = 1.0f / 4096.0f;

__device__ __forceinline__ unsigned short f16b(float x) {
    _Float16 h = (_Float16)x;                       // v_cvt_f16_f32 (RNE)
    return __builtin_bit_cast(unsigned short, h);
}
__device__ __forceinline__ float f16tof(unsigned short b) {
    return (float)__builtin_bit_cast(_Float16, b);
}
__device__ __forceinline__ half8 ntloadB(const unsigned short* p) {
    ushort8 u = __builtin_nontemporal_load(reinterpret_cast<const ushort8*>(p));
    return __builtin_bit_cast(half8, u);
}

// ---------------------------------------------------------------------------
// K1 (unchanged): W*4096 (gate rows 0..63, noise rows 64..127) split fp16
// hi/lo, packed for 32x32x16 B-fragments:
//   [kstep16 kk (stride 4096)][ntile32 nt (stride 1024)]{ hi 512 | lo 512 }
//   lane l holds B[k = kk*16 + (l>>5)*8 + j][n = nt*32 + (l&31)]
// ---------------------------------------------------------------------------
__global__ void prep_w(const float* __restrict__ Wg, const float* __restrict__ Wn,
                       unsigned short* __restrict__ wsB)
{
    const int idx = blockIdx.x * blockDim.x + threadIdx.x;   // 0..32767
    const int n   = idx >> 8;      // output row 0..127
    const int K8  = idx & 255;     // k-octet
    const float* src = (n < 64) ? (Wg + (size_t)n * D_DIM)
                                : (Wn + (size_t)(n - 64) * D_DIM);
    f32x4 a = *reinterpret_cast<const f32x4*>(src + K8 * 8);
    f32x4 b = *reinterpret_cast<const f32x4*>(src + K8 * 8 + 4);

    float v[8] = {a[0], a[1], a[2], a[3], b[0], b[1], b[2], b[3]};
    union { unsigned short u[8]; half8 s; } H, L;
#pragma unroll
    for (int j = 0; j < 8; ++j) {
        float xs = v[j] * WSCALE;
        unsigned short h = f16b(xs);
        H.u[j] = h;
        L.u[j] = f16b(xs - f16tof(h));
    }
    const int kk   = K8 >> 1;             // kstep16 index 0..127
    const int koct = K8 & 1;              // k-octet within kstep
    const int lane = koct * 32 + (n & 31);
    const size_t base = (size_t)kk * 4096 + (size_t)(n >> 5) * 1024 + (size_t)lane * 8;
    *reinterpret_cast<half8*>(wsB + base)       = H.s;
    *reinterpret_cast<half8*>(wsB + base + 512) = L.s;
}

// ---------------------------------------------------------------------------
// K2 v6: barrier-free direct-global MFMA. No staging LDS at all: each lane
// loads its own A-fragment bytes (32B/kstep, contiguous) straight from hs;
// the 4 nt-waves of a WG read identical addresses -> L1 serves 3 of 4.
// B fragments nontemporal (keep L1 for hs). Register double-buffer at chunk
// granularity for both A (fp32) and B. Zero barriers in the K-loop; a bare
// s_barrier every 2 chunks bounds wave drift for L1 locality.
// TM=32 tokens, 4 waves (w = nt), grid 512 = 2 independent WGs/CU.
// LDS: only the 32x132 f32 logits tile (16896 B).
// ---------------------------------------------------------------------------
__global__ __launch_bounds__(256, 2)
void noisy_topk_router(const float* __restrict__ hs,
                       const unsigned short* __restrict__ wsB,
                       const float* __restrict__ nz,
                       float* __restrict__ out)
{
    __shared__ __align__(16) float logits[TM * OSTR];   // 16896 B

    const int tid  = threadIdx.x;
    const int lane = tid & 63;
    const int w    = tid >> 6;          // wave id = n-tile (experts w*32..+31? no: 4 nt of 32 -> 128 outs)
    const int nt   = w;                 // n-tile: output cols nt*32..+31
    const int t0   = blockIdx.x * TM;

    const int mrow = lane & 31;         // token row within tile
    const int koct = lane >> 5;         // k-octet within kstep
    const float* abase = hs + (size_t)(t0 + mrow) * D_DIM + koct * 8;
    const unsigned short* bbase = wsB + (size_t)nt * 1024 + (size_t)lane * 8;

    f32x16 accP, accX0, accX1;
#pragma unroll
    for (int i = 0; i < 16; ++i) { accP[i] = 0.f; accX0[i] = 0.f; accX1[i] = 0.f; }

    f32x4 A0[4][2], A1[4][2];
    half8 bh0[4], bl0[4], bh1[4], bl1[4];

    auto loadA = [&](int chunk, f32x4 (*A)[2]) {
#pragma unroll
        for (int ks = 0; ks < 4; ++ks) {
            const float* p = abase + (size_t)(chunk * 4 + ks) * 16;
            A[ks][0] = *reinterpret_cast<const f32x4*>(p);
            A[ks][1] = *reinterpret_cast<const f32x4*>(p + 4);
        }
    };
    auto loadB = [&](int chunk, half8* bh, half8* bl) {
#pragma unroll
        for (int ks = 0; ks < 4; ++ks) {
            const unsigned short* p = bbase + (size_t)(chunk * 4 + ks) * 4096;
            bh[ks] = ntloadB(p);
            bl[ks] = ntloadB(p + 512);
        }
    };
    auto body = [&](f32x4 (*A)[2], const half8* bh, const half8* bl) {
#pragma unroll
        for (int ks = 0; ks < 4; ++ks) {
            float v[8] = {A[ks][0][0], A[ks][0][1], A[ks][0][2], A[ks][0][3],
                          A[ks][1][0], A[ks][1][1], A[ks][1][2], A[ks][1][3]};
            union { unsigned short u[8]; half8 s; } H, L;
#pragma unroll
            for (int j = 0; j < 8; ++j) {
                unsigned short h = f16b(v[j]);
                H.u[j] = h;
                L.u[j] = f16b(v[j] - f16tof(h));
            }
            accP  = __builtin_amdgcn_mfma_f32_32x32x16_f16(H.s, bh[ks], accP,  0, 0, 0);
            accX0 = __builtin_amdgcn_mfma_f32_32x32x16_f16(H.s, bl[ks], accX0, 0, 0, 0);
            accX1 = __builtin_amdgcn_mfma_f32_32x32x16_f16(L.s, bh[ks], accX1, 0, 0, 0);
        }
    };

    // prologue: chunk 0 into buffer 0
    loadA(0, A0);
    loadB(0, bh0, bl0);

#pragma unroll 1
    for (int cc = 0; cc < NCH / 2; ++cc) {
        const int e = 2 * cc;
        // chunk e: prefetch e+1, compute from buffer 0
        loadA(e + 1, A1);
        loadB(e + 1, bh1, bl1);
        body(A0, bh0, bl0);
        // chunk e+1: prefetch e+2, compute from buffer 1
        if (e + 2 < NCH) {
            loadA(e + 2, A0);
            loadB(e + 2, bh0, bl0);
        }
        body(A1, bh1, bl1);
        __builtin_amdgcn_s_barrier();   // drift bound only; no memory semantics needed
    }

    // ---- epilogue: accs -> logit tile ----
    {
        const int colb  = nt * 32 + (lane & 31);
        const int rbase = 4 * (lane >> 5);
#pragma unroll
        for (int rr = 0; rr < 16; ++rr) {
            const int row = rbase + (rr & 3) + 8 * (rr >> 2);
            logits[row * OSTR + colb] = (accP[rr] + accX0[rr] + accX1[rr]) * INV_WSC;
        }
    }
    __syncthreads();

    // ---- wave-parallel epilogue: wave w owns tokens w*8..w*8+7,
    //      expert-per-lane (lane = expert e) ----
    float* gout = out + (size_t)NTOK * TOPK * 2;
    for (int tt = 0; tt < 8; ++tt) {
        const int tl  = w * 8 + tt;
        const int tok = t0 + tl;
        float gsc = logits[tl * OSTR + lane];
        float nl  = logits[tl * OSTR + 64 + lane];
        float nzv = __builtin_nontemporal_load(nz + (size_t)tok * NEXP + lane);
        float sp  = fmaxf(nl, 0.0f) + log1pf(expf(-fabsf(nl)));   // softplus
        float le  = fmaf(nzv, sp, gsc);

        float mx = le;
#pragma unroll
        for (int d = 32; d > 0; d >>= 1) mx = fmaxf(mx, __shfl_xor(mx, d));
        float pe = expf(le - mx);
        float s  = pe;
#pragma unroll
        for (int d = 32; d > 0; d >>= 1) s += __shfl_xor(s, d);
        float g = pe * (1.0f / s);

        gout[(size_t)tok * NEXP + lane] = g;

        // top-8 by repeated wave argmax; tie-break: lowest index
        float v = g;
        float keepv = 0.0f;
        int   keepi = 0;
#pragma unroll
        for (int it = 0; it < TOPK; ++it) {
            float m  = v;
            int   mi = lane;
#pragma unroll
            for (int d = 32; d > 0; d >>= 1) {
                float om = __shfl_xor(m, d);
                int   oi = __shfl_xor(mi, d);
                bool take = (om > m) || (om == m && oi < mi);
                m  = take ? om : m;
                mi = take ? oi : mi;
            }
            if (lane == it) { keepv = m; keepi = mi; }
            if (lane == mi) v = -1.0f;      // extracted; gates>0 so never re-wins
        }
        if (lane < TOPK) {
            out[(size_t)tok * TOPK + lane] = keepv;
            out[(size_t)NTOK * TOPK + (size_t)tok * TOPK + lane] = (float)keepi;
        }
    }
}

extern "C" void kernel_launch(void* const* d_in, const int* in_sizes, int n_in,
                              void* d_out, int out_size, void* d_ws, size_t ws_size,
                              hipStream_t stream) {
    const float* hs = (const float*)d_in[0];   // [4,4096,2048]
    const float* Wg = (const float*)d_in[1];   // [64,2048]
    const float* Wn = (const float*)d_in[2];   // [64,2048]
    const float* nz = (const float*)d_in[3];   // [4,4096,64]
    float* out = (float*)d_out;
    unsigned short* wsB = (unsigned short*)d_ws;   // 1 MB B-fragment pack

    prep_w<<<64, 512, 0, stream>>>(Wg, Wn, wsB);
    noisy_topk_router<<<NTOK / TM, 256, 0, stream>>>(hs, wsB, nz, out);
}

// Round 7
// 229.581 us; speedup vs baseline: 1.2839x; 1.2839x over previous
//
#include <hip/hip_runtime.h>
#include <math.h>

typedef __attribute__((ext_vector_type(8)))  _Float16       half8;
typedef __attribute__((ext_vector_type(8)))  unsigned short ushort8;
typedef __attribute__((ext_vector_type(4)))  float          f32x4;
typedef __attribute__((ext_vector_type(16))) float          f32x16;

constexpr int D_DIM = 2048;
constexpr int NEXP  = 64;
constexpr int TOPK  = 8;
constexpr int NTOK  = 16384;        // B*S
constexpr int TM    = 32;           // tokens per WG
constexpr int BK    = 64;           // K per staged chunk (4 ksteps of 16)
constexpr int NCH   = D_DIM / BK;   // 32 chunks
constexpr int OSTR  = 132;          // logit tile row stride (floats)
constexpr float WSCALE  = 4096.0f;
constexpr float INV_WSC = 1.0f / 4096.0f;

__device__ __forceinline__ unsigned short f16b(float x) {
    _Float16 h = (_Float16)x;                       // v_cvt_f16_f32 (RNE)
    return __builtin_bit_cast(unsigned short, h);
}
__device__ __forceinline__ float f16tof(unsigned short b) {
    return (float)__builtin_bit_cast(_Float16, b);
}
__device__ __forceinline__ f32x4 ntload4(const float* p) {
    return __builtin_nontemporal_load(reinterpret_cast<const f32x4*>(p));
}
// LDS-visibility barrier WITHOUT vmcnt drain: ds_writes complete (lgkmcnt),
// outstanding global loads (register dests) stay in flight across it.
__device__ __forceinline__ void bar_lds() {
    asm volatile("s_waitcnt lgkmcnt(0)\n\ts_barrier" ::: "memory");
}

// ---------------------------------------------------------------------------
// K1 (unchanged): W*4096 (gate rows 0..63, noise rows 64..127) split fp16
// hi/lo, packed for 32x32x16 B-fragments:
//   [kstep16 kk (stride 4096)][ntile32 nt (stride 1024)]{ hi 512 | lo 512 }
//   lane l holds B[k = kk*16 + (l>>5)*8 + j][n = nt*32 + (l&31)]
// ---------------------------------------------------------------------------
__global__ void prep_w(const float* __restrict__ Wg, const float* __restrict__ Wn,
                       unsigned short* __restrict__ wsB)
{
    const int idx = blockIdx.x * blockDim.x + threadIdx.x;   // 0..32767
    const int n   = idx >> 8;      // output row 0..127
    const int K8  = idx & 255;     // k-octet
    const float* src = (n < 64) ? (Wg + (size_t)n * D_DIM)
                                : (Wn + (size_t)(n - 64) * D_DIM);
    f32x4 a = *reinterpret_cast<const f32x4*>(src + K8 * 8);
    f32x4 b = *reinterpret_cast<const f32x4*>(src + K8 * 8 + 4);

    float v[8] = {a[0], a[1], a[2], a[3], b[0], b[1], b[2], b[3]};
    union { unsigned short u[8]; half8 s; } H, L;
#pragma unroll
    for (int j = 0; j < 8; ++j) {
        float xs = v[j] * WSCALE;
        unsigned short h = f16b(xs);
        H.u[j] = h;
        L.u[j] = f16b(xs - f16tof(h));
    }
    const int kk   = K8 >> 1;             // kstep16 index 0..127
    const int koct = K8 & 1;              // k-octet within kstep
    const int lane = koct * 32 + (n & 31);
    const size_t base = (size_t)kk * 4096 + (size_t)(n >> 5) * 1024 + (size_t)lane * 8;
    *reinterpret_cast<half8*>(wsB + base)       = H.s;
    *reinterpret_cast<half8*>(wsB + base + 512) = L.s;
}

// ---------------------------------------------------------------------------
// K2 v7: never-drain pipeline. K-loop barriers are lgkmcnt-only (no vmcnt
// drain) so global loads span barriers; hs prefetch 2 chunks deep; B loads
// 1 chunk deep. TM=32, 512 WGs -> 2 independent WGs/CU (stall cover).
// 8 waves = (nt 0..3) x (kh 0..1): kh splits the 4 ksteps of a chunk ->
// B L2 traffic halved; partial accs summed in the logit tile.
// Stage: fragment-linear fp16 hi/lo, unit index XOR ks (conflict-free reads).
// LDS: 2 stage bufs x 4096 ushorts (16 KB) union'd with 32x132 f32 logits.
// ---------------------------------------------------------------------------
__global__ __launch_bounds__(512, 4)
void noisy_topk_router(const float* __restrict__ hs,
                       const unsigned short* __restrict__ wsB,
                       const float* __restrict__ nz,
                       float* __restrict__ out)
{
    __shared__ __align__(16) char smem[16896];
    unsigned short* stage  = reinterpret_cast<unsigned short*>(smem);
    float*          logits = reinterpret_cast<float*>(smem);

    const int tid  = threadIdx.x;
    const int lane = tid & 63;
    const int w    = tid >> 6;
    const int nt   = w & 3;             // n-tile: experts nt*32..+31
    const int kh   = w >> 2;            // K-half: ksteps kh*2, kh*2+1 of each chunk
    const int t0   = blockIdx.x * TM;

    // --- staging role: thread t -> row r (0..31), 4 k-elems k4..k4+3 ---
    const int r    = tid >> 4;
    const int k4   = (tid & 15) * 4;
    const int ksw  = k4 >> 4;           // kstep within chunk
    const int kin  = k4 & 15;
    const int koct = kin >> 3;
    const int pos  = kin & 7;           // 0 or 4
    const int unitp = ((koct << 5) + r) ^ ksw;           // XOR-swizzled 16B unit
    const int whi  = ksw * 1024 + unitp * 8 + pos;       // ushort offset, hi frag
    const int wlo  = whi + 512;                          // lo frag
    const float* hrow = hs + (size_t)(t0 + r) * D_DIM + k4;

    // --- B base ---
    const unsigned short* bbase = wsB + (size_t)nt * 1024 + (size_t)lane * 8;

    f32x16 accP, accX0, accX1;
#pragma unroll
    for (int i = 0; i < 16; ++i) { accP[i] = 0.f; accX0[i] = 0.f; accX1[i] = 0.f; }

    half8 bh0[2], bl0[2], bh1[2], bl1[2];

    auto loadB = [&](int c, half8* bh, half8* bl) {
#pragma unroll
        for (int i = 0; i < 2; ++i) {
            const unsigned short* p = bbase + (size_t)(c * 4 + kh * 2 + i) * 4096;
            bh[i] = *reinterpret_cast<const half8*>(p);
            bl[i] = *reinterpret_cast<const half8*>(p + 512);
        }
    };

    auto cvt_write = [&](f32x4 a, unsigned short* buf) {
        float v[4] = {a[0], a[1], a[2], a[3]};
        unsigned int Hp[2], Lp[2];
#pragma unroll
        for (int q = 0; q < 2; ++q) {
            unsigned short h0 = f16b(v[2*q]);
            unsigned short h1 = f16b(v[2*q+1]);
            unsigned short l0 = f16b(v[2*q]   - f16tof(h0));
            unsigned short l1 = f16b(v[2*q+1] - f16tof(h1));
            Hp[q] = (unsigned int)h0 | ((unsigned int)h1 << 16);
            Lp[q] = (unsigned int)l0 | ((unsigned int)l1 << 16);
        }
        *reinterpret_cast<uint2*>(buf + whi) = make_uint2(Hp[0], Hp[1]);
        *reinterpret_cast<uint2*>(buf + wlo) = make_uint2(Lp[0], Lp[1]);
    };

    auto body = [&](const unsigned short* sb, const half8* bh, const half8* bl) {
#pragma unroll
        for (int i = 0; i < 2; ++i) {
            const int ks  = kh * 2 + i;
            const int off = ks * 1024 + ((lane ^ ks) * 8);
            half8 ahi = *reinterpret_cast<const half8*>(sb + off);
            half8 alo = *reinterpret_cast<const half8*>(sb + off + 512);
            accP  = __builtin_amdgcn_mfma_f32_32x32x16_f16(ahi, bh[i], accP,  0, 0, 0);
            accX0 = __builtin_amdgcn_mfma_f32_32x32x16_f16(ahi, bl[i], accX0, 0, 0, 0);
            accX1 = __builtin_amdgcn_mfma_f32_32x32x16_f16(alo, bh[i], accX1, 0, 0, 0);
        }
    };

    // prologue: B(0); stage chunk 0; hs(1) in flight
    loadB(0, bh0, bl0);
    f32x4 a0 = ntload4(hrow);
    f32x4 Pc = ntload4(hrow + BK);          // for chunk 1
    cvt_write(a0, stage);
    bar_lds();

#pragma unroll 1
    for (int cc = 0; cc < 15; ++cc) {
        const int e = 2 * cc;
        // ---- chunk e (buf0, B0) ----
        loadB(e + 1, bh1, bl1);
        __builtin_amdgcn_sched_barrier(0);
        f32x4 Pa = ntload4(hrow + (e + 2) * BK);
        __builtin_amdgcn_sched_barrier(0);
        body(stage, bh0, bl0);
        cvt_write(Pc, stage + 4096);
        bar_lds();
        // ---- chunk e+1 (buf1, B1) ----
        loadB(e + 2, bh0, bl0);
        __builtin_amdgcn_sched_barrier(0);
        f32x4 Pb = ntload4(hrow + (e + 3) * BK);
        __builtin_amdgcn_sched_barrier(0);
        body(stage + 4096, bh1, bl1);
        cvt_write(Pa, stage);
        bar_lds();
        Pc = Pb;
    }
    // ---- chunk 30 (buf0, B0) ----
    loadB(31, bh1, bl1);
    body(stage, bh0, bl0);
    cvt_write(Pc, stage + 4096);            // hs(31), issued one chunk ago
    bar_lds();
    // ---- chunk 31 (buf1, B1) ----
    body(stage + 4096, bh1, bl1);
    __syncthreads();                        // full drain before LDS reuse

    // ---- epilogue: kh partial sums -> logit tile ----
    {
        const int colb  = nt * 32 + (lane & 31);
        const int rbase = 4 * (lane >> 5);
        if (kh == 0) {
#pragma unroll
            for (int rr = 0; rr < 16; ++rr) {
                const int row = rbase + (rr & 3) + 8 * (rr >> 2);
                logits[row * OSTR + colb] = (accP[rr] + accX0[rr] + accX1[rr]) * INV_WSC;
            }
        }
        __syncthreads();
        if (kh == 1) {
#pragma unroll
            for (int rr = 0; rr < 16; ++rr) {
                const int row = rbase + (rr & 3) + 8 * (rr >> 2);
                logits[row * OSTR + colb] += (accP[rr] + accX0[rr] + accX1[rr]) * INV_WSC;
            }
        }
        __syncthreads();
    }

    // ---- wave-parallel epilogue: wave w owns tokens w*4..w*4+3,
    //      expert-per-lane (lane = expert e) ----
    float* gout = out + (size_t)NTOK * TOPK * 2;
    for (int tt = 0; tt < 4; ++tt) {
        const int tl  = w * 4 + tt;
        const int tok = t0 + tl;
        float gsc = logits[tl * OSTR + lane];
        float nl  = logits[tl * OSTR + 64 + lane];
        float nzv = __builtin_nontemporal_load(nz + (size_t)tok * NEXP + lane);
        float sp  = fmaxf(nl, 0.0f) + log1pf(expf(-fabsf(nl)));   // softplus
        float le  = fmaf(nzv, sp, gsc);

        float mx = le;
#pragma unroll
        for (int d = 32; d > 0; d >>= 1) mx = fmaxf(mx, __shfl_xor(mx, d));
        float pe = expf(le - mx);
        float s  = pe;
#pragma unroll
        for (int d = 32; d > 0; d >>= 1) s += __shfl_xor(s, d);
        float g = pe * (1.0f / s);

        gout[(size_t)tok * NEXP + lane] = g;

        // top-8 by repeated wave argmax; tie-break: lowest index
        float v = g;
        float keepv = 0.0f;
        int   keepi = 0;
#pragma unroll
        for (int it = 0; it < TOPK; ++it) {
            float m  = v;
            int   mi = lane;
#pragma unroll
            for (int d = 32; d > 0; d >>= 1) {
                float om = __shfl_xor(m, d);
                int   oi = __shfl_xor(mi, d);
                bool take = (om > m) || (om == m && oi < mi);
                m  = take ? om : m;
                mi = take ? oi : mi;
            }
            if (lane == it) { keepv = m; keepi = mi; }
            if (lane == mi) v = -1.0f;      // extracted; gates>0 so never re-wins
        }
        if (lane < TOPK) {
            out[(size_t)tok * TOPK + lane] = keepv;
            out[(size_t)NTOK * TOPK + (size_t)tok * TOPK + lane] = (float)keepi;
        }
    }
}

extern "C" void kernel_launch(void* const* d_in, const int* in_sizes, int n_in,
                              void* d_out, int out_size, void* d_ws, size_t ws_size,
                              hipStream_t stream) {
    const float* hs = (const float*)d_in[0];   // [4,4096,2048]
    const float* Wg = (const float*)d_in[1];   // [64,2048]
    const float* Wn = (const float*)d_in[2];   // [64,2048]
    const float* nz = (const float*)d_in[3];   // [4,4096,64]
    float* out = (float*)d_out;
    unsigned short* wsB = (unsigned short*)d_ws;   // 1 MB B-fragment pack

    prep_w<<<64, 512, 0, stream>>>(Wg, Wn, wsB);
    noisy_topk_router<<<NTOK / TM, 512, 0, stream>>>(hs, wsB, nz, out);
}